// Round 11
// baseline (470.728 us; speedup 1.0000x reference)
//
#include <hip/hip_runtime.h>

#define L 4096
#define D 512
#define NCH 16   // context n-chunks (256 n per chunk)

typedef __bf16 bf16x8 __attribute__((ext_vector_type(8)));
typedef float  f32x4  __attribute__((ext_vector_type(4)));

__device__ __forceinline__ void load_lds16(const void* g, void* l) {
    __builtin_amdgcn_global_load_lds(
        (const __attribute__((address_space(1))) void*)g,
        (__attribute__((address_space(3))) void*)l, 16, 0, 0);
}

__device__ __forceinline__ void barrier_mem() {
    asm volatile("" ::: "memory");
    __builtin_amdgcn_s_barrier();
    asm volatile("" ::: "memory");
}

// ---------------------------------------------------------------------------
// merged f32 -> bf16 conversion for x, Wqkv, Wout (contiguous dst regions).
// Also zeroes the 64 per-bh completion counters used by context_fused
// (stream-ordered before it; runs every graph replay -> counters always 0).
// ---------------------------------------------------------------------------
#define NX8  (8 * 4096 * 512 / 8)
#define NW18 (1536 * 512 / 8)
#define NW28 (512 * 512 / 8)
__global__ __launch_bounds__(256) void convert_all(const float* __restrict__ x,
                                                   const float* __restrict__ Wq,
                                                   const float* __restrict__ Wo,
                                                   __bf16* __restrict__ dst,
                                                   int* __restrict__ cnt) {
    if (blockIdx.x == 0 && threadIdx.x < 64) cnt[threadIdx.x] = 0;
    int i = blockIdx.x * 256 + threadIdx.x;
    if (i >= NX8 + NW18 + NW28) return;
    const float* s;
    if (i < NX8)             s = x  + (size_t)i * 8;
    else if (i < NX8 + NW18) s = Wq + (size_t)(i - NX8) * 8;
    else                     s = Wo + (size_t)(i - NX8 - NW18) * 8;
    float4 a = ((const float4*)s)[0], b = ((const float4*)s)[1];
    bf16x8 o = {(__bf16)a.x, (__bf16)a.y, (__bf16)a.z, (__bf16)a.w,
                (__bf16)b.x, (__bf16)b.y, (__bf16)b.z, (__bf16)b.w};
    *(bf16x8*)(dst + (size_t)i * 8) = o;
}

// ---------------------------------------------------------------------------
// 256x256-tile TN bf16 MFMA GEMM, 8-PHASE schedule (unchanged from R10 —
// control kernel; counters should reproduce 72us / MfmaUtil 27%).
// ---------------------------------------------------------------------------
template <int M, int N, int K, typename CT>
__global__ __launch_bounds__(512, 2) void gemm_bf16_8ph(
    const __bf16* __restrict__ A, size_t aStride,
    const __bf16* __restrict__ B, size_t bStride,
    CT* __restrict__ C, size_t cStride,
    const float* __restrict__ bias) {
    __shared__ __align__(16) __bf16 sB[2][256 * 64];   // 64 KB
    __shared__ __align__(16) __bf16 sA[2][256 * 64];   // 64 KB
    constexpr int NT = K / 64;                          // 8
    const int b  = blockIdx.z;
    const int m0 = blockIdx.y * 256;
    const int n0 = blockIdx.x * 256;
    const int t    = threadIdx.x;
    const int wave = t >> 6, lane = t & 63;
    const int wm = (wave >> 2) * 128;   // 2 M-halves
    const int wn = (wave & 3) * 64;     // 4 N-quads
    const int fr = lane & 15, g = lane >> 4;
    const __bf16* Ab = A + (size_t)b * aStride + (size_t)m0 * K;
    const __bf16* Bb = B + (size_t)b * bStride + (size_t)n0 * K;
    CT* Cb = C + (size_t)b * cStride;

    const __bf16* pA_[4];
    const __bf16* pB_[4];
#pragma unroll
    for (int k = 0; k < 4; ++k) {
        const int gi = k * 512 + t, row = gi >> 3, cc = gi & 7;
        pA_[k] = Ab + (size_t)row * K + (cc ^ (row & 7)) * 8;
        pB_[k] = Bb + (size_t)row * K + (cc ^ (row & 7)) * 8;
    }
    const int lc0 = ((0 + g) ^ (fr & 7)) * 8;
    const int lc1 = ((4 + g) ^ (fr & 7)) * 8;

    f32x4 acc[8][4];
#pragma unroll
    for (int i = 0; i < 8; i++)
#pragma unroll
        for (int j = 0; j < 4; j++) acc[i][j] = (f32x4)(0.0f);

    auto stageH = [&](int kt, int pb, int h) {
#pragma unroll
        for (int k = h * 2; k < h * 2 + 2; ++k) {
            load_lds16(pA_[k] + kt * 64, &sA[pb][(k * 512 + t) * 8]);
            load_lds16(pB_[k] + kt * 64, &sB[pb][(k * 512 + t) * 8]);
        }
    };

    stageH(0, 0, 0);
    stageH(0, 0, 1);

    bf16x8 fB[4], fA[4];
#pragma unroll
    for (int kt = 0; kt < NT; ++kt) {
        const int p = kt & 1;
        // ---------------- ph0 ----------------
        if (kt + 1 < NT) {
            stageH(kt + 1, p ^ 1, 0);
            asm volatile("s_waitcnt vmcnt(4)" ::: "memory");
        } else {
            asm volatile("s_waitcnt vmcnt(0)" ::: "memory");
        }
        barrier_mem();
#pragma unroll
        for (int j = 0; j < 4; ++j)
            fB[j] = *(const bf16x8*)&sB[p][(wn + j * 16 + fr) * 64 + lc0];
#pragma unroll
        for (int i = 0; i < 4; ++i)
            fA[i] = *(const bf16x8*)&sA[p][(wm + i * 16 + fr) * 64 + lc0];
        asm volatile("s_waitcnt lgkmcnt(0)" ::: "memory");
        __builtin_amdgcn_sched_barrier(0);
        __builtin_amdgcn_s_setprio(1);
#pragma unroll
        for (int i = 0; i < 4; ++i)
#pragma unroll
            for (int j = 0; j < 4; ++j)
                acc[i][j] = __builtin_amdgcn_mfma_f32_16x16x32_bf16(fA[i], fB[j], acc[i][j], 0, 0, 0);
        __builtin_amdgcn_s_setprio(0);
        barrier_mem();
        // ---------------- ph1 ----------------
#pragma unroll
        for (int i = 0; i < 4; ++i)
            fA[i] = *(const bf16x8*)&sA[p][(wm + 64 + i * 16 + fr) * 64 + lc0];
        if (kt + 1 < NT) stageH(kt + 1, p ^ 1, 1);
        barrier_mem();
        asm volatile("s_waitcnt lgkmcnt(0)" ::: "memory");
        __builtin_amdgcn_sched_barrier(0);
        __builtin_amdgcn_s_setprio(1);
#pragma unroll
        for (int i = 0; i < 4; ++i)
#pragma unroll
            for (int j = 0; j < 4; ++j)
                acc[4 + i][j] = __builtin_amdgcn_mfma_f32_16x16x32_bf16(fA[i], fB[j], acc[4 + i][j], 0, 0, 0);
        __builtin_amdgcn_s_setprio(0);
        barrier_mem();
        // ---------------- ph2 ----------------
#pragma unroll
        for (int j = 0; j < 4; ++j)
            fB[j] = *(const bf16x8*)&sB[p][(wn + j * 16 + fr) * 64 + lc1];
#pragma unroll
        for (int i = 0; i < 4; ++i)
            fA[i] = *(const bf16x8*)&sA[p][(wm + i * 16 + fr) * 64 + lc1];
        barrier_mem();
        asm volatile("s_waitcnt lgkmcnt(0)" ::: "memory");
        __builtin_amdgcn_sched_barrier(0);
        __builtin_amdgcn_s_setprio(1);
#pragma unroll
        for (int i = 0; i < 4; ++i)
#pragma unroll
            for (int j = 0; j < 4; ++j)
                acc[i][j] = __builtin_amdgcn_mfma_f32_16x16x32_bf16(fA[i], fB[j], acc[i][j], 0, 0, 0);
        __builtin_amdgcn_s_setprio(0);
        barrier_mem();
        // ---------------- ph3 ----------------
#pragma unroll
        for (int i = 0; i < 4; ++i)
            fA[i] = *(const bf16x8*)&sA[p][(wm + 64 + i * 16 + fr) * 64 + lc1];
        barrier_mem();
        asm volatile("s_waitcnt lgkmcnt(0)" ::: "memory");
        __builtin_amdgcn_sched_barrier(0);
        __builtin_amdgcn_s_setprio(1);
#pragma unroll
        for (int i = 0; i < 4; ++i)
#pragma unroll
            for (int j = 0; j < 4; ++j)
                acc[4 + i][j] = __builtin_amdgcn_mfma_f32_16x16x32_bf16(fA[i], fB[j], acc[4 + i][j], 0, 0, 0);
        __builtin_amdgcn_s_setprio(0);
        barrier_mem();
    }

    const int rb = g * 4;
    float bv[4];
#pragma unroll
    for (int j = 0; j < 4; ++j) bv[j] = bias ? bias[n0 + wn + j * 16 + fr] : 0.0f;
#pragma unroll
    for (int i = 0; i < 8; ++i) {
#pragma unroll
        for (int r = 0; r < 4; ++r) {
            const int m = m0 + wm + i * 16 + rb + r;
            CT* rowp = Cb + (size_t)m * N + n0 + wn + fr;
#pragma unroll
            for (int j = 0; j < 4; ++j)
                rowp[j * 16] = (CT)(acc[i][j][r] + bv[j]);
        }
    }
}

// ---------------------------------------------------------------------------
// context_fused: replaces kstats + context_mfma + ctx_reduce (3 kernels -> 1).
// Per (chunk,bh) block: LOCAL k-row max over this chunk's 256 n (4-lane
// shfl_xor reduce; the 4 threads owning a row are wave-contiguous), local
// sumexp, un-normalized partial ctxp[chunk][bh][d][e] = sum exp(k-m_c)*v.
// Online-softmax rescale at combine: ctx = sum_c p_c*exp(m_c-M); S = sum_c
// s_c*exp(m_c-M); ctxT = ctx/S -- algebraically identical to global-max.
// Last-block-reduces: threadfence + device atomicAdd(cnt[bh]); 16th block
// acquires (fence) and reduces the 16 L3-warm partials, writes bf16 ctxT
// transposed. cnt zeroed by convert_all each replay (stream-ordered).
// ---------------------------------------------------------------------------
#define SKS 264   // LDS bf16 row stride (256 data + 8 pad)
__global__ __launch_bounds__(256) void context_fused(const __bf16* __restrict__ qkv,
                                                     float* __restrict__ ctxp,
                                                     float* __restrict__ mstat,
                                                     float* __restrict__ sstat,
                                                     int* __restrict__ cnt,
                                                     __bf16* __restrict__ ctxT) {
    __shared__ __align__(16) __bf16 smem[2 * 64 * SKS];  // 67.6 KB; reused as f32 red[4][4096]
    __shared__ int isLast;
    __bf16* sk = smem;
    __bf16* sv = smem + 64 * SKS;
    const int chunk = blockIdx.x;
    const int bh = blockIdx.y;
    const int b = bh >> 3, h = bh & 7;
    const __bf16* kbase = qkv + (size_t)b * 1536 * L + (size_t)(512 + h * 64) * L;
    const __bf16* vbase = qkv + (size_t)b * 1536 * L + (size_t)(1024 + h * 64) * L;
    const int t = threadIdx.x;

    // stage: thread t -> row d = t>>2, n-quarter (t&3)*64; local max + exp
    {
        const int d = t >> 2, noff = (t & 3) * 64;
        const int n0 = chunk * 256;
        const __bf16* kp = kbase + (size_t)d * L + n0 + noff;
        const __bf16* vp = vbase + (size_t)d * L + n0 + noff;
        bf16x8 kk[8];
        float m = -1e30f;
#pragma unroll
        for (int c = 0; c < 8; c++) {
            kk[c] = *(const bf16x8*)(kp + c * 8);
            bf16x8 vv = *(const bf16x8*)(vp + c * 8);
            *(bf16x8*)&sv[d * SKS + noff + c * 8] = vv;
#pragma unroll
            for (int j = 0; j < 8; j++) m = fmaxf(m, (float)kk[c][j]);
        }
        // max across the 4 threads of row d (lane groups of 4, aligned)
        m = fmaxf(m, __shfl_xor(m, 1, 64));
        m = fmaxf(m, __shfl_xor(m, 2, 64));
        float s = 0.f;
#pragma unroll
        for (int c = 0; c < 8; c++) {
            bf16x8 ek;
#pragma unroll
            for (int j = 0; j < 8; j++) {
                float e = __expf((float)kk[c][j] - m);
                s += e;
                ek[j] = (__bf16)e;
            }
            *(bf16x8*)&sk[d * SKS + noff + c * 8] = ek;
        }
        s += __shfl_xor(s, 1, 64);
        s += __shfl_xor(s, 2, 64);
        if ((t & 3) == 0) {
            mstat[((size_t)chunk * 64 + bh) * 64 + d] = m;
            sstat[((size_t)chunk * 64 + bh) * 64 + d] = s;
        }
    }
    __syncthreads();

    // MFMA: wave w covers n in [w*64, w*64+64)
    const int wave = t >> 6, lane = t & 63;
    const int fr = lane & 15, kq = (lane >> 4) * 8;
    f32x4 acc[4][4];
#pragma unroll
    for (int i = 0; i < 4; i++)
#pragma unroll
        for (int j = 0; j < 4; j++) acc[i][j] = (f32x4)(0.0f);
#pragma unroll
    for (int kh = 0; kh < 2; kh++) {
        const int koff = wave * 64 + kh * 32 + kq;
        bf16x8 af[4], bfr[4];
#pragma unroll
        for (int i = 0; i < 4; i++) {
            af[i]  = *(const bf16x8*)&sk[(i * 16 + fr) * SKS + koff];
            bfr[i] = *(const bf16x8*)&sv[(i * 16 + fr) * SKS + koff];
        }
#pragma unroll
        for (int i = 0; i < 4; i++)
#pragma unroll
            for (int j = 0; j < 4; j++)
                acc[i][j] = __builtin_amdgcn_mfma_f32_16x16x32_bf16(af[i], bfr[j], acc[i][j], 0, 0, 0);
    }
    __syncthreads();   // MFMA LDS reads done; safe to overwrite smem

    // cross-wave reduce via LDS: red[w][d*64+e]
    float* red = (float*)smem;   // 4 * 4096 f32 = 64 KB
    const int col = lane & 15, rbase = (lane >> 4) * 4;
#pragma unroll
    for (int i = 0; i < 4; i++)
#pragma unroll
        for (int j = 0; j < 4; j++)
#pragma unroll
            for (int r = 0; r < 4; r++) {
                const int dd = i * 16 + rbase + r;
                const int ee = j * 16 + col;
                red[wave * 4096 + dd * 64 + ee] = acc[i][j][r];
            }
    __syncthreads();
    float* cp = ctxp + ((size_t)chunk * 64 + bh) * 4096;
#pragma unroll
    for (int gg = 0; gg < 4; gg++) {
        const int idx = t * 16 + gg * 4;
        f32x4 s = *(const f32x4*)&red[idx];
        s += *(const f32x4*)&red[4096 + idx];
        s += *(const f32x4*)&red[8192 + idx];
        s += *(const f32x4*)&red[12288 + idx];
        *(f32x4*)&cp[idx] = s;
    }

    // ---- completion: last block for this bh reduces all 16 chunks ----
    __threadfence();                               // release partial + stats
    if (t == 0) isLast = (atomicAdd(&cnt[bh], 1) == NCH - 1);
    __syncthreads();
    if (!isLast) return;
    __threadfence();                               // acquire others' writes

    const int rd = t >> 2;            // d: 0..63
    const int re0 = (t & 3) * 16;     // e start (16 e's per thread)
    float M = -1e30f;
#pragma unroll
    for (int ch = 0; ch < NCH; ch++)
        M = fmaxf(M, mstat[((size_t)ch * 64 + bh) * 64 + rd]);
    float S = 0.f;
    float w[NCH];
#pragma unroll
    for (int ch = 0; ch < NCH; ch++) {
        w[ch] = __expf(mstat[((size_t)ch * 64 + bh) * 64 + rd] - M);
        S += sstat[((size_t)ch * 64 + bh) * 64 + rd] * w[ch];
    }
    const float inv = 1.0f / S;
    f32x4 a4[4];
#pragma unroll
    for (int k = 0; k < 4; k++) a4[k] = (f32x4)(0.0f);
#pragma unroll
    for (int ch = 0; ch < NCH; ch++) {
        const float* pc = ctxp + ((size_t)ch * 64 + bh) * 4096 + rd * 64 + re0;
#pragma unroll
        for (int k = 0; k < 4; k++) {
            f32x4 v = *(const f32x4*)&pc[k * 4];
            a4[k] += v * w[ch];
        }
    }
    __bf16* o = ctxT + (size_t)bh * 4096;
#pragma unroll
    for (int k = 0; k < 4; k++)
#pragma unroll
        for (int j = 0; j < 4; j++)
            o[(re0 + k * 4 + j) * 64 + rd] = (__bf16)(a4[k][j] * inv);
}

// ---------------------------------------------------------------------------
// pv_fused: per (bh, 256-col tile): q-softmax (unnormalized exp in LDS bf16)
// + MFMA 256x64 K=64 against ctxT, normalize in epilogue, write bf16 outT.
// ---------------------------------------------------------------------------
#define SPS 66   // LDS row stride (bf16)
__global__ __launch_bounds__(256) void pv_fused(__bf16* __restrict__ qkv,
                                                const __bf16* __restrict__ ctxT) {
    __shared__ __align__(16) __bf16 sp[256 * SPS];   // p rows [n][d]
    __shared__ __align__(16) __bf16 sctx[64 * SPS];  // ctxT rows [e][d]
    __shared__ float sinv[256];
    const int tileN = blockIdx.x;
    const int bh = blockIdx.y;
    const int b = bh >> 3, h = bh & 7;
    const int t = threadIdx.x;
    const int n0 = tileN * 256;
    const __bf16* qbase = qkv + (size_t)b * 1536 * L + (size_t)(h * 64) * L;

    {   // stage ctxT (64x64 bf16)
        const int e = t >> 2, c = t & 3;
        const bf16x8* src = (const bf16x8*)(ctxT + ((size_t)bh * 64 + e) * 64 + c * 16);
        *(bf16x8*)&sctx[e * SPS + c * 16] = src[0];
        *(bf16x8*)&sctx[e * SPS + c * 16 + 8] = src[1];
    }

    // read bf16 q column (coalesced across lanes), exp, sum, stage
    float m = -1e30f;
    float qv[64];
#pragma unroll
    for (int d = 0; d < 64; d++) {
        qv[d] = (float)qbase[(size_t)d * L + n0 + t];
        m = fmaxf(m, qv[d]);
    }
    float s = 0.f;
#pragma unroll
    for (int d0 = 0; d0 < 64; d0 += 8) {
        bf16x8 ek;
#pragma unroll
        for (int j = 0; j < 8; j++) {
            float e = __expf(qv[d0 + j] - m);
            s += e;
            ek[j] = (__bf16)e;
        }
        *(bf16x8*)&sp[t * SPS + d0] = ek;
    }
    sinv[t] = 1.0f / s;
    __syncthreads();

    // MFMA: out[n][e] = sum_d p[n][d] * ctxT[e][d]; 4 waves x 64 rows
    const int wave = t >> 6, lane = t & 63;
    const int wm = wave * 64;
    const int fr = lane & 15, kq = (lane >> 4) * 8;
    f32x4 acc[4][4];
#pragma unroll
    for (int i = 0; i < 4; i++)
#pragma unroll
        for (int j = 0; j < 4; j++) acc[i][j] = (f32x4)(0.0f);
#pragma unroll
    for (int kh = 0; kh < 2; kh++) {
        bf16x8 af[4], bfr[4];
#pragma unroll
        for (int i = 0; i < 4; i++)
            af[i] = *(const bf16x8*)&sp[(wm + i * 16 + fr) * SPS + kh * 32 + kq];
#pragma unroll
        for (int j = 0; j < 4; j++)
            bfr[j] = *(const bf16x8*)&sctx[(j * 16 + fr) * SPS + kh * 32 + kq];
#pragma unroll
        for (int i = 0; i < 4; i++)
#pragma unroll
            for (int j = 0; j < 4; j++)
                acc[i][j] = __builtin_amdgcn_mfma_f32_16x16x32_bf16(af[i], bfr[j], acc[i][j], 0, 0, 0);
    }

    // epilogue: normalize by 1/s[n], write bf16 outT[b][n][h*64+e]
    __bf16* ob = qkv + (size_t)b * 1536 * L + (size_t)512 * L;
    const int col = lane & 15, rbase = (lane >> 4) * 4;
#pragma unroll
    for (int i = 0; i < 4; i++) {
#pragma unroll
        for (int r = 0; r < 4; r++) {
            const int nl = wm + i * 16 + rbase + r;
            const float inv = sinv[nl];
            const size_t rowoff = (size_t)(n0 + nl) * 512 + h * 64;
#pragma unroll
            for (int j = 0; j < 4; j++)
                ob[rowoff + j * 16 + col] = (__bf16)(acc[i][j][r] * inv);
        }
    }
}

// ---------------------------------------------------------------------------
extern "C" void kernel_launch(void* const* d_in, const int* in_sizes, int n_in,
                              void* d_out, int out_size, void* d_ws, size_t ws_size,
                              hipStream_t stream) {
    const float* x    = (const float*)d_in[0];
    const float* Wqkv = (const float*)d_in[1];
    const float* Wout = (const float*)d_in[2];
    const float* bout = (const float*)d_in[3];
    float* y = (float*)d_out;

    __bf16* qkv   = (__bf16*)d_ws;                               // 8*1536*4096 bf16
    float*  ctxp  = (float*)(qkv + (size_t)8 * 1536 * L);        // NCH*64*4096 f32
    __bf16* xb    = (__bf16*)(ctxp + (size_t)NCH * 64 * 4096);   // 8*4096*512 bf16
    __bf16* Wqb   = xb + (size_t)8 * 4096 * 512;                 // 1536*512 bf16
    __bf16* Wob   = Wqb + (size_t)1536 * 512;                    // 512*512 bf16
    float*  mstat = (float*)(Wob + (size_t)512 * 512);           // NCH*64*64 f32
    float*  sstat = mstat + (size_t)NCH * 64 * 64;               // NCH*64*64 f32
    int*    cnt   = (int*)(sstat + (size_t)NCH * 64 * 64);       // 64 int
    __bf16* ctxT  = (__bf16*)(cnt + 64);                         // 64*4096 bf16

    const int convBlocks = (NX8 + NW18 + NW28 + 255) / 256;
    convert_all<<<dim3(convBlocks), 256, 0, stream>>>(x, Wqkv, Wout, xb, cnt);

    // qkv[b][o][l] = sum_d Wqkv[o][d] * x[b][l][d]   (M=1536, N=4096, K=512), bf16 out
    gemm_bf16_8ph<1536, 4096, 512, __bf16><<<dim3(4096 / 256, 1536 / 256, 8), 512, 0, stream>>>(
        Wqb, 0, xb, (size_t)4096 * 512, qkv, (size_t)1536 * 4096, nullptr);

    context_fused<<<dim3(NCH, 64), 256, 0, stream>>>(qkv, ctxp, mstat, sstat, cnt, ctxT);
    pv_fused<<<dim3(L / 256, 64), 256, 0, stream>>>(qkv, ctxT);

    // y[b][l][d] = sum_c outT[b][l][c] * Wout[d][c] + bout[d]  (M=4096, N=512, K=512), f32 out
    const __bf16* outT = qkv + (size_t)512 * L;
    gemm_bf16_8ph<4096, 512, 512, float><<<dim3(512 / 256, 4096 / 256, 8), 512, 0, stream>>>(
        outT, (size_t)1536 * L, Wob, 0, y, (size_t)4096 * 512, bout);
}

// Round 14
// 254.523 us; speedup vs baseline: 1.8495x; 1.8495x over previous
//
#include <hip/hip_runtime.h>

#define L 4096
#define D 512
#define NCH 16   // context n-chunks (256 n per chunk)

typedef __bf16 bf16x8 __attribute__((ext_vector_type(8)));
typedef float  f32x4  __attribute__((ext_vector_type(4)));

__device__ __forceinline__ void load_lds16(const void* g, void* l) {
    __builtin_amdgcn_global_load_lds(
        (const __attribute__((address_space(1))) void*)g,
        (__attribute__((address_space(3))) void*)l, 16, 0, 0);
}

__device__ __forceinline__ void barrier_mem() {
    asm volatile("" ::: "memory");
    __builtin_amdgcn_s_barrier();
    asm volatile("" ::: "memory");
}

// ---------------------------------------------------------------------------
// merged f32 -> bf16 conversion for x, Wqkv, Wout (contiguous dst regions)
// ---------------------------------------------------------------------------
#define NX8  (8 * 4096 * 512 / 8)
#define NW18 (1536 * 512 / 8)
#define NW28 (512 * 512 / 8)
__global__ __launch_bounds__(256) void convert_all(const float* __restrict__ x,
                                                   const float* __restrict__ Wq,
                                                   const float* __restrict__ Wo,
                                                   __bf16* __restrict__ dst) {
    int i = blockIdx.x * 256 + threadIdx.x;
    if (i >= NX8 + NW18 + NW28) return;
    const float* s;
    if (i < NX8)             s = x  + (size_t)i * 8;
    else if (i < NX8 + NW18) s = Wq + (size_t)(i - NX8) * 8;
    else                     s = Wo + (size_t)(i - NX8 - NW18) * 8;
    float4 a = ((const float4*)s)[0], b = ((const float4*)s)[1];
    bf16x8 o = {(__bf16)a.x, (__bf16)a.y, (__bf16)a.z, (__bf16)a.w,
                (__bf16)b.x, (__bf16)b.y, (__bf16)b.z, (__bf16)b.w};
    *(bf16x8*)(dst + (size_t)i * 8) = o;
}

// ---------------------------------------------------------------------------
// 256x256-tile TN bf16 MFMA GEMM, 8-PHASE schedule (unchanged — control
// kernel; counters should reproduce 72us / MfmaUtil 27%).
// ---------------------------------------------------------------------------
template <int M, int N, int K, typename CT>
__global__ __launch_bounds__(512, 2) void gemm_bf16_8ph(
    const __bf16* __restrict__ A, size_t aStride,
    const __bf16* __restrict__ B, size_t bStride,
    CT* __restrict__ C, size_t cStride,
    const float* __restrict__ bias) {
    __shared__ __align__(16) __bf16 sB[2][256 * 64];   // 64 KB
    __shared__ __align__(16) __bf16 sA[2][256 * 64];   // 64 KB
    constexpr int NT = K / 64;                          // 8
    const int b  = blockIdx.z;
    const int m0 = blockIdx.y * 256;
    const int n0 = blockIdx.x * 256;
    const int t    = threadIdx.x;
    const int wave = t >> 6, lane = t & 63;
    const int wm = (wave >> 2) * 128;   // 2 M-halves
    const int wn = (wave & 3) * 64;     // 4 N-quads
    const int fr = lane & 15, g = lane >> 4;
    const __bf16* Ab = A + (size_t)b * aStride + (size_t)m0 * K;
    const __bf16* Bb = B + (size_t)b * bStride + (size_t)n0 * K;
    CT* Cb = C + (size_t)b * cStride;

    const __bf16* pA_[4];
    const __bf16* pB_[4];
#pragma unroll
    for (int k = 0; k < 4; ++k) {
        const int gi = k * 512 + t, row = gi >> 3, cc = gi & 7;
        pA_[k] = Ab + (size_t)row * K + (cc ^ (row & 7)) * 8;
        pB_[k] = Bb + (size_t)row * K + (cc ^ (row & 7)) * 8;
    }
    const int lc0 = ((0 + g) ^ (fr & 7)) * 8;
    const int lc1 = ((4 + g) ^ (fr & 7)) * 8;

    f32x4 acc[8][4];
#pragma unroll
    for (int i = 0; i < 8; i++)
#pragma unroll
        for (int j = 0; j < 4; j++) acc[i][j] = (f32x4)(0.0f);

    auto stageH = [&](int kt, int pb, int h) {
#pragma unroll
        for (int k = h * 2; k < h * 2 + 2; ++k) {
            load_lds16(pA_[k] + kt * 64, &sA[pb][(k * 512 + t) * 8]);
            load_lds16(pB_[k] + kt * 64, &sB[pb][(k * 512 + t) * 8]);
        }
    };

    stageH(0, 0, 0);
    stageH(0, 0, 1);

    bf16x8 fB[4], fA[4];
#pragma unroll
    for (int kt = 0; kt < NT; ++kt) {
        const int p = kt & 1;
        // ---------------- ph0 ----------------
        if (kt + 1 < NT) {
            stageH(kt + 1, p ^ 1, 0);
            asm volatile("s_waitcnt vmcnt(4)" ::: "memory");
        } else {
            asm volatile("s_waitcnt vmcnt(0)" ::: "memory");
        }
        barrier_mem();
#pragma unroll
        for (int j = 0; j < 4; ++j)
            fB[j] = *(const bf16x8*)&sB[p][(wn + j * 16 + fr) * 64 + lc0];
#pragma unroll
        for (int i = 0; i < 4; ++i)
            fA[i] = *(const bf16x8*)&sA[p][(wm + i * 16 + fr) * 64 + lc0];
        asm volatile("s_waitcnt lgkmcnt(0)" ::: "memory");
        __builtin_amdgcn_sched_barrier(0);
        __builtin_amdgcn_s_setprio(1);
#pragma unroll
        for (int i = 0; i < 4; ++i)
#pragma unroll
            for (int j = 0; j < 4; ++j)
                acc[i][j] = __builtin_amdgcn_mfma_f32_16x16x32_bf16(fA[i], fB[j], acc[i][j], 0, 0, 0);
        __builtin_amdgcn_s_setprio(0);
        barrier_mem();
        // ---------------- ph1 ----------------
#pragma unroll
        for (int i = 0; i < 4; ++i)
            fA[i] = *(const bf16x8*)&sA[p][(wm + 64 + i * 16 + fr) * 64 + lc0];
        if (kt + 1 < NT) stageH(kt + 1, p ^ 1, 1);
        barrier_mem();
        asm volatile("s_waitcnt lgkmcnt(0)" ::: "memory");
        __builtin_amdgcn_sched_barrier(0);
        __builtin_amdgcn_s_setprio(1);
#pragma unroll
        for (int i = 0; i < 4; ++i)
#pragma unroll
            for (int j = 0; j < 4; ++j)
                acc[4 + i][j] = __builtin_amdgcn_mfma_f32_16x16x32_bf16(fA[i], fB[j], acc[4 + i][j], 0, 0, 0);
        __builtin_amdgcn_s_setprio(0);
        barrier_mem();
        // ---------------- ph2 ----------------
#pragma unroll
        for (int j = 0; j < 4; ++j)
            fB[j] = *(const bf16x8*)&sB[p][(wn + j * 16 + fr) * 64 + lc1];
#pragma unroll
        for (int i = 0; i < 4; ++i)
            fA[i] = *(const bf16x8*)&sA[p][(wm + i * 16 + fr) * 64 + lc1];
        barrier_mem();
        asm volatile("s_waitcnt lgkmcnt(0)" ::: "memory");
        __builtin_amdgcn_sched_barrier(0);
        __builtin_amdgcn_s_setprio(1);
#pragma unroll
        for (int i = 0; i < 4; ++i)
#pragma unroll
            for (int j = 0; j < 4; ++j)
                acc[i][j] = __builtin_amdgcn_mfma_f32_16x16x32_bf16(fA[i], fB[j], acc[i][j], 0, 0, 0);
        __builtin_amdgcn_s_setprio(0);
        barrier_mem();
        // ---------------- ph3 ----------------
#pragma unroll
        for (int i = 0; i < 4; ++i)
            fA[i] = *(const bf16x8*)&sA[p][(wm + 64 + i * 16 + fr) * 64 + lc1];
        barrier_mem();
        asm volatile("s_waitcnt lgkmcnt(0)" ::: "memory");
        __builtin_amdgcn_sched_barrier(0);
        __builtin_amdgcn_s_setprio(1);
#pragma unroll
        for (int i = 0; i < 4; ++i)
#pragma unroll
            for (int j = 0; j < 4; ++j)
                acc[4 + i][j] = __builtin_amdgcn_mfma_f32_16x16x32_bf16(fA[i], fB[j], acc[4 + i][j], 0, 0, 0);
        __builtin_amdgcn_s_setprio(0);
        barrier_mem();
    }

    const int rb = g * 4;
    float bv[4];
#pragma unroll
    for (int j = 0; j < 4; ++j) bv[j] = bias ? bias[n0 + wn + j * 16 + fr] : 0.0f;
#pragma unroll
    for (int i = 0; i < 8; ++i) {
#pragma unroll
        for (int r = 0; r < 4; ++r) {
            const int m = m0 + wm + i * 16 + rb + r;
            CT* rowp = Cb + (size_t)m * N + n0 + wn + fr;
#pragma unroll
            for (int j = 0; j < 4; ++j)
                rowp[j * 16] = (CT)(acc[i][j][r] + bv[j]);
        }
    }
}

// ---------------------------------------------------------------------------
// context_local: replaces kstats + context_mfma (NO cross-block sync — the
// R11 post-mortem: __threadfence per block = L2 writeback/invalidate across
// 8 XCDs, 250us of idle serialization. Kernel boundary provides ordering
// for free instead). Per (chunk,bh) block: LOCAL k-row max over this
// chunk's 256 n (4-lane shfl reduce), local sumexp, un-normalized partial
// ctxp[chunk][bh][d][e] = sum_n exp(k-m_c)*v; stats to mstat/sstat.
// ---------------------------------------------------------------------------
#define SKS 264   // LDS bf16 row stride (256 data + 8 pad)
__global__ __launch_bounds__(256) void context_local(const __bf16* __restrict__ qkv,
                                                     float* __restrict__ ctxp,
                                                     float* __restrict__ mstat,
                                                     float* __restrict__ sstat) {
    __shared__ __align__(16) __bf16 smem[2 * 64 * SKS];  // 67.6 KB; reused as f32 red[4][4096]
    __bf16* sk = smem;
    __bf16* sv = smem + 64 * SKS;
    const int chunk = blockIdx.x;
    const int bh = blockIdx.y;
    const int b = bh >> 3, h = bh & 7;
    const __bf16* kbase = qkv + (size_t)b * 1536 * L + (size_t)(512 + h * 64) * L;
    const __bf16* vbase = qkv + (size_t)b * 1536 * L + (size_t)(1024 + h * 64) * L;
    const int t = threadIdx.x;

    // stage: thread t -> row d = t>>2, n-quarter (t&3)*64; local max + exp
    {
        const int d = t >> 2, noff = (t & 3) * 64;
        const int n0 = chunk * 256;
        const __bf16* kp = kbase + (size_t)d * L + n0 + noff;
        const __bf16* vp = vbase + (size_t)d * L + n0 + noff;
        bf16x8 kk[8];
        float m = -1e30f;
#pragma unroll
        for (int c = 0; c < 8; c++) {
            kk[c] = *(const bf16x8*)(kp + c * 8);
            bf16x8 vv = *(const bf16x8*)(vp + c * 8);
            *(bf16x8*)&sv[d * SKS + noff + c * 8] = vv;
#pragma unroll
            for (int j = 0; j < 8; j++) m = fmaxf(m, (float)kk[c][j]);
        }
        // max across the 4 threads of row d (lane groups of 4, aligned)
        m = fmaxf(m, __shfl_xor(m, 1, 64));
        m = fmaxf(m, __shfl_xor(m, 2, 64));
        float s = 0.f;
#pragma unroll
        for (int c = 0; c < 8; c++) {
            bf16x8 ek;
#pragma unroll
            for (int j = 0; j < 8; j++) {
                float e = __expf((float)kk[c][j] - m);
                s += e;
                ek[j] = (__bf16)e;
            }
            *(bf16x8*)&sk[d * SKS + noff + c * 8] = ek;
        }
        s += __shfl_xor(s, 1, 64);
        s += __shfl_xor(s, 2, 64);
        if ((t & 3) == 0) {
            mstat[((size_t)chunk * 64 + bh) * 64 + d] = m;
            sstat[((size_t)chunk * 64 + bh) * 64 + d] = s;
        }
    }
    __syncthreads();

    // MFMA: wave w covers n in [w*64, w*64+64)
    const int wave = t >> 6, lane = t & 63;
    const int fr = lane & 15, kq = (lane >> 4) * 8;
    f32x4 acc[4][4];
#pragma unroll
    for (int i = 0; i < 4; i++)
#pragma unroll
        for (int j = 0; j < 4; j++) acc[i][j] = (f32x4)(0.0f);
#pragma unroll
    for (int kh = 0; kh < 2; kh++) {
        const int koff = wave * 64 + kh * 32 + kq;
        bf16x8 af[4], bfr[4];
#pragma unroll
        for (int i = 0; i < 4; i++) {
            af[i]  = *(const bf16x8*)&sk[(i * 16 + fr) * SKS + koff];
            bfr[i] = *(const bf16x8*)&sv[(i * 16 + fr) * SKS + koff];
        }
#pragma unroll
        for (int i = 0; i < 4; i++)
#pragma unroll
            for (int j = 0; j < 4; j++)
                acc[i][j] = __builtin_amdgcn_mfma_f32_16x16x32_bf16(af[i], bfr[j], acc[i][j], 0, 0, 0);
    }
    __syncthreads();   // MFMA LDS reads done; safe to overwrite smem

    // cross-wave reduce via LDS: red[w][d*64+e]
    float* red = (float*)smem;   // 4 * 4096 f32 = 64 KB
    const int col = lane & 15, rbase = (lane >> 4) * 4;
#pragma unroll
    for (int i = 0; i < 4; i++)
#pragma unroll
        for (int j = 0; j < 4; j++)
#pragma unroll
            for (int r = 0; r < 4; r++) {
                const int dd = i * 16 + rbase + r;
                const int ee = j * 16 + col;
                red[wave * 4096 + dd * 64 + ee] = acc[i][j][r];
            }
    __syncthreads();
    float* cp = ctxp + ((size_t)chunk * 64 + bh) * 4096;
#pragma unroll
    for (int gg = 0; gg < 4; gg++) {
        const int idx = t * 16 + gg * 4;
        f32x4 s = *(const f32x4*)&red[idx];
        s += *(const f32x4*)&red[4096 + idx];
        s += *(const f32x4*)&red[8192 + idx];
        s += *(const f32x4*)&red[12288 + idx];
        *(f32x4*)&cp[idx] = s;
    }
}

// ---------------------------------------------------------------------------
// ctx_combine: online-softmax combine across chunks (ordering via kernel
// boundary — no fences/atomics). ctx[d][e] = sum_c P_c*exp(m_c-M) /
// sum_c s_c*exp(m_c-M); transpose -> bf16 ctxT[bh][e][d]. grid 256.
// ---------------------------------------------------------------------------
__global__ __launch_bounds__(256) void ctx_combine(const float* __restrict__ ctxp,
                                                   const float* __restrict__ mstat,
                                                   const float* __restrict__ sstat,
                                                   __bf16* __restrict__ ctxT) {
    const int bh = blockIdx.x >> 2, quarter = blockIdx.x & 3;
    const int t = threadIdx.x;
    const int flat = quarter * 1024 + t * 4;   // d-major: d = flat>>6, e0 = flat&63
    const int d = flat >> 6, e0 = flat & 63;
    float M = -1e30f;
#pragma unroll
    for (int ch = 0; ch < NCH; ch++)
        M = fmaxf(M, mstat[((size_t)ch * 64 + bh) * 64 + d]);
    float S = 0.f;
    float w[NCH];
#pragma unroll
    for (int ch = 0; ch < NCH; ch++) {
        w[ch] = __expf(mstat[((size_t)ch * 64 + bh) * 64 + d] - M);
        S += sstat[((size_t)ch * 64 + bh) * 64 + d] * w[ch];
    }
    const float inv = 1.0f / S;
    f32x4 s = (f32x4)(0.0f);
#pragma unroll
    for (int ch = 0; ch < NCH; ch++) {
        f32x4 v = *(const f32x4*)&ctxp[((size_t)ch * 64 + bh) * 4096 + flat];
        s += v * w[ch];
    }
    __bf16* o = ctxT + (size_t)bh * 4096;
#pragma unroll
    for (int j = 0; j < 4; j++) o[(e0 + j) * 64 + d] = (__bf16)(s[j] * inv);
}

// ---------------------------------------------------------------------------
// pv_fused: per (bh, 256-col tile): q-softmax (unnormalized exp in LDS bf16)
// + MFMA 256x64 K=64 against ctxT, normalize in epilogue, write bf16 outT.
// ---------------------------------------------------------------------------
#define SPS 66   // LDS row stride (bf16)
__global__ __launch_bounds__(256) void pv_fused(__bf16* __restrict__ qkv,
                                                const __bf16* __restrict__ ctxT) {
    __shared__ __align__(16) __bf16 sp[256 * SPS];   // p rows [n][d]
    __shared__ __align__(16) __bf16 sctx[64 * SPS];  // ctxT rows [e][d]
    __shared__ float sinv[256];
    const int tileN = blockIdx.x;
    const int bh = blockIdx.y;
    const int b = bh >> 3, h = bh & 7;
    const int t = threadIdx.x;
    const int n0 = tileN * 256;
    const __bf16* qbase = qkv + (size_t)b * 1536 * L + (size_t)(h * 64) * L;

    {   // stage ctxT (64x64 bf16)
        const int e = t >> 2, c = t & 3;
        const bf16x8* src = (const bf16x8*)(ctxT + ((size_t)bh * 64 + e) * 64 + c * 16);
        *(bf16x8*)&sctx[e * SPS + c * 16] = src[0];
        *(bf16x8*)&sctx[e * SPS + c * 16 + 8] = src[1];
    }

    // read bf16 q column (coalesced across lanes), exp, sum, stage
    float m = -1e30f;
    float qv[64];
#pragma unroll
    for (int d = 0; d < 64; d++) {
        qv[d] = (float)qbase[(size_t)d * L + n0 + t];
        m = fmaxf(m, qv[d]);
    }
    float s = 0.f;
#pragma unroll
    for (int d0 = 0; d0 < 64; d0 += 8) {
        bf16x8 ek;
#pragma unroll
        for (int j = 0; j < 8; j++) {
            float e = __expf(qv[d0 + j] - m);
            s += e;
            ek[j] = (__bf16)e;
        }
        *(bf16x8*)&sp[t * SPS + d0] = ek;
    }
    sinv[t] = 1.0f / s;
    __syncthreads();

    // MFMA: out[n][e] = sum_d p[n][d] * ctxT[e][d]; 4 waves x 64 rows
    const int wave = t >> 6, lane = t & 63;
    const int wm = wave * 64;
    const int fr = lane & 15, kq = (lane >> 4) * 8;
    f32x4 acc[4][4];
#pragma unroll
    for (int i = 0; i < 4; i++)
#pragma unroll
        for (int j = 0; j < 4; j++) acc[i][j] = (f32x4)(0.0f);
#pragma unroll
    for (int kh = 0; kh < 2; kh++) {
        bf16x8 af[4], bfr[4];
#pragma unroll
        for (int i = 0; i < 4; i++)
            af[i] = *(const bf16x8*)&sp[(wm + i * 16 + fr) * SPS + kh * 32 + kq];
#pragma unroll
        for (int j = 0; j < 4; j++)
            bfr[j] = *(const bf16x8*)&sctx[(j * 16 + fr) * SPS + kh * 32 + kq];
#pragma unroll
        for (int i = 0; i < 4; i++)
#pragma unroll
            for (int j = 0; j < 4; j++)
                acc[i][j] = __builtin_amdgcn_mfma_f32_16x16x32_bf16(af[i], bfr[j], acc[i][j], 0, 0, 0);
    }

    // epilogue: normalize by 1/s[n], write bf16 outT[b][n][h*64+e]
    __bf16* ob = qkv + (size_t)b * 1536 * L + (size_t)512 * L;
    const int col = lane & 15, rbase = (lane >> 4) * 4;
#pragma unroll
    for (int i = 0; i < 4; i++) {
#pragma unroll
        for (int r = 0; r < 4; r++) {
            const int nl = wm + i * 16 + rbase + r;
            const float inv = sinv[nl];
            const size_t rowoff = (size_t)(n0 + nl) * 512 + h * 64;
#pragma unroll
            for (int j = 0; j < 4; j++)
                ob[rowoff + j * 16 + col] = (__bf16)(acc[i][j][r] * inv);
        }
    }
}

// ---------------------------------------------------------------------------
extern "C" void kernel_launch(void* const* d_in, const int* in_sizes, int n_in,
                              void* d_out, int out_size, void* d_ws, size_t ws_size,
                              hipStream_t stream) {
    const float* x    = (const float*)d_in[0];
    const float* Wqkv = (const float*)d_in[1];
    const float* Wout = (const float*)d_in[2];
    const float* bout = (const float*)d_in[3];
    float* y = (float*)d_out;

    __bf16* qkv   = (__bf16*)d_ws;                               // 8*1536*4096 bf16
    float*  ctxp  = (float*)(qkv + (size_t)8 * 1536 * L);        // NCH*64*4096 f32
    __bf16* xb    = (__bf16*)(ctxp + (size_t)NCH * 64 * 4096);   // 8*4096*512 bf16
    __bf16* Wqb   = xb + (size_t)8 * 4096 * 512;                 // 1536*512 bf16
    __bf16* Wob   = Wqb + (size_t)1536 * 512;                    // 512*512 bf16
    float*  mstat = (float*)(Wob + (size_t)512 * 512);           // NCH*64*64 f32
    float*  sstat = mstat + (size_t)NCH * 64 * 64;               // NCH*64*64 f32
    __bf16* ctxT  = (__bf16*)(sstat + (size_t)NCH * 64 * 64);    // 64*4096 bf16

    const int convBlocks = (NX8 + NW18 + NW28 + 255) / 256;
    convert_all<<<dim3(convBlocks), 256, 0, stream>>>(x, Wqkv, Wout, xb);

    // qkv[b][o][l] = sum_d Wqkv[o][d] * x[b][l][d]   (M=1536, N=4096, K=512), bf16 out
    gemm_bf16_8ph<1536, 4096, 512, __bf16><<<dim3(4096 / 256, 1536 / 256, 8), 512, 0, stream>>>(
        Wqb, 0, xb, (size_t)4096 * 512, qkv, (size_t)1536 * 4096, nullptr);

    context_local<<<dim3(NCH, 64), 256, 0, stream>>>(qkv, ctxp, mstat, sstat);
    ctx_combine<<<dim3(256), 256, 0, stream>>>(ctxp, mstat, sstat, ctxT);
    pv_fused<<<dim3(L / 256, 64), 256, 0, stream>>>(qkv, ctxT);

    // y[b][l][d] = sum_c outT[b][l][c] * Wout[d][c] + bout[d]  (M=4096, N=512, K=512), f32 out
    const __bf16* outT = qkv + (size_t)512 * L;
    gemm_bf16_8ph<4096, 512, 512, float><<<dim3(512 / 256, 4096 / 256, 8), 512, 0, stream>>>(
        outT, (size_t)1536 * L, Wob, 0, y, (size_t)4096 * 512, bout);
}

// Round 15
// 249.259 us; speedup vs baseline: 1.8885x; 1.0211x over previous
//
#include <hip/hip_runtime.h>

#define L 4096
#define D 512
#define NCH 16   // context n-chunks (256 n per chunk)

typedef __bf16 bf16x8 __attribute__((ext_vector_type(8)));
typedef float  f32x4  __attribute__((ext_vector_type(4)));

__device__ __forceinline__ void load_lds16(const void* g, void* l) {
    __builtin_amdgcn_global_load_lds(
        (const __attribute__((address_space(1))) void*)g,
        (__attribute__((address_space(3))) void*)l, 16, 0, 0);
}

__device__ __forceinline__ void barrier_mem() {
    asm volatile("" ::: "memory");
    __builtin_amdgcn_s_barrier();
    asm volatile("" ::: "memory");
}

// ---------------------------------------------------------------------------
// merged f32 -> bf16 conversion for x, Wqkv, Wout (contiguous dst regions)
// ---------------------------------------------------------------------------
#define NX8  (8 * 4096 * 512 / 8)
#define NW18 (1536 * 512 / 8)
#define NW28 (512 * 512 / 8)
__global__ __launch_bounds__(256) void convert_all(const float* __restrict__ x,
                                                   const float* __restrict__ Wq,
                                                   const float* __restrict__ Wo,
                                                   __bf16* __restrict__ dst) {
    int i = blockIdx.x * 256 + threadIdx.x;
    if (i >= NX8 + NW18 + NW28) return;
    const float* s;
    if (i < NX8)             s = x  + (size_t)i * 8;
    else if (i < NX8 + NW18) s = Wq + (size_t)(i - NX8) * 8;
    else                     s = Wo + (size_t)(i - NX8 - NW18) * 8;
    float4 a = ((const float4*)s)[0], b = ((const float4*)s)[1];
    bf16x8 o = {(__bf16)a.x, (__bf16)a.y, (__bf16)a.z, (__bf16)a.w,
                (__bf16)b.x, (__bf16)b.y, (__bf16)b.z, (__bf16)b.w};
    *(bf16x8*)(dst + (size_t)i * 8) = o;
}

// ---------------------------------------------------------------------------
// 256x256-tile TN bf16 MFMA GEMM — WAVE-SLIP schedule.
// R14 post-mortem: all 5 prior schedules serialized {LDS service -> MFMA}
// inside barrier-locked phases (both pipes <=40% busy, 29% MfmaUtil).
// Fix: ONE barrier per K-tile + counted-lgkm cascade so 4-read groups
// retire UNDER each 16-MFMA block, and waves slip out of phase (LDS pipe
// and MFMA pipe concurrently fed across waves).
// Per K-tile: {vmcnt(0) [covered: kt's loads issued 1 K-tile ago, ~2000cyc
//   > 900cyc HBM lat]; barrier [all waves' loads landed + all p^1 frag
//   reads drained (each wave's lgkm(0) precedes its arrival)]; stage kt+1
//   (8 gloads -> p^1, post-barrier = WAR-safe); cascade:
//   issue B0,A0,A1(12); lgkm(4)->MFMA16(A0xB0) [A1 under];
//   issue B1,A2; lgkm(8)->MFMA16(A1xB0) [B1,A2 under];
//   issue A3; lgkm(4)->MFMA16(A2xB1) [A3 under];
//   lgkm(0)->MFMA16(A3xB1)}.
// All waits proven by per-wave in-order LDS retirement; global_load_lds is
// vmcnt-class (does not perturb lgkm counts). sched_barrier(0) after each
// counted lgkm (rule 18). Swizzle unchanged (bank-conflict 0 measured).
// ---------------------------------------------------------------------------
template <int M, int N, int K, typename CT>
__global__ __launch_bounds__(512, 2) void gemm_bf16_ws(
    const __bf16* __restrict__ A, size_t aStride,
    const __bf16* __restrict__ B, size_t bStride,
    CT* __restrict__ C, size_t cStride,
    const float* __restrict__ bias) {
    __shared__ __align__(16) __bf16 sB[2][256 * 64];   // 64 KB
    __shared__ __align__(16) __bf16 sA[2][256 * 64];   // 64 KB
    constexpr int NT = K / 64;                          // 8
    const int b  = blockIdx.z;
    const int m0 = blockIdx.y * 256;
    const int n0 = blockIdx.x * 256;
    const int t    = threadIdx.x;
    const int wave = t >> 6, lane = t & 63;
    const int wm = (wave >> 2) * 128;   // 2 M-halves
    const int wn = (wave & 3) * 64;     // 4 N-quads
    const int fr = lane & 15, g = lane >> 4;
    const __bf16* Ab = A + (size_t)b * aStride + (size_t)m0 * K;
    const __bf16* Bb = B + (size_t)b * bStride + (size_t)n0 * K;
    CT* Cb = C + (size_t)b * cStride;

    const __bf16* pA_[4];
    const __bf16* pB_[4];
#pragma unroll
    for (int k = 0; k < 4; ++k) {
        const int gi = k * 512 + t, row = gi >> 3, cc = gi & 7;
        pA_[k] = Ab + (size_t)row * K + (cc ^ (row & 7)) * 8;
        pB_[k] = Bb + (size_t)row * K + (cc ^ (row & 7)) * 8;
    }
    const int lc0 = ((0 + g) ^ (fr & 7)) * 8;
    const int lc1 = ((4 + g) ^ (fr & 7)) * 8;

    f32x4 acc[8][4];
#pragma unroll
    for (int i = 0; i < 8; i++)
#pragma unroll
        for (int j = 0; j < 4; j++) acc[i][j] = (f32x4)(0.0f);

    auto stageT = [&](int kt, int pb) {
#pragma unroll
        for (int k = 0; k < 4; ++k) {
            load_lds16(pA_[k] + kt * 64, &sA[pb][(k * 512 + t) * 8]);
            load_lds16(pB_[k] + kt * 64, &sB[pb][(k * 512 + t) * 8]);
        }
    };

    // prologue: stage K-tile 0 fully (8 loads)
    stageT(0, 0);

#pragma unroll
    for (int kt = 0; kt < NT; ++kt) {
        const int p = kt & 1;
        asm volatile("s_waitcnt vmcnt(0)" ::: "memory");   // kt landed (covered)
        barrier_mem();                                     // single barrier/K-tile
        if (kt + 1 < NT) stageT(kt + 1, p ^ 1);            // WAR-safe (post-barrier)

        bf16x8 fB0[4], fB1[4], fA0[4], fA1[4], fA2[4], fA3[4];
        // group 1: B0, A0, A1 (12 reads outstanding)
#pragma unroll
        for (int j = 0; j < 4; ++j)
            fB0[j] = *(const bf16x8*)&sB[p][(wn + j * 16 + fr) * 64 + lc0];
#pragma unroll
        for (int i = 0; i < 4; ++i)
            fA0[i] = *(const bf16x8*)&sA[p][(wm + i * 16 + fr) * 64 + lc0];
#pragma unroll
        for (int i = 0; i < 4; ++i)
            fA1[i] = *(const bf16x8*)&sA[p][(wm + 64 + i * 16 + fr) * 64 + lc0];
        asm volatile("s_waitcnt lgkmcnt(4)" ::: "memory");  // B0+A0 done, A1 out
        __builtin_amdgcn_sched_barrier(0);
        __builtin_amdgcn_s_setprio(1);
#pragma unroll
        for (int i = 0; i < 4; ++i)
#pragma unroll
            for (int j = 0; j < 4; ++j)
                acc[i][j] = __builtin_amdgcn_mfma_f32_16x16x32_bf16(fA0[i], fB0[j], acc[i][j], 0, 0, 0);
        __builtin_amdgcn_s_setprio(0);
        // group 2: B1, A2 issued; A1's MFMA runs while they retire
#pragma unroll
        for (int j = 0; j < 4; ++j)
            fB1[j] = *(const bf16x8*)&sB[p][(wn + j * 16 + fr) * 64 + lc1];
#pragma unroll
        for (int i = 0; i < 4; ++i)
            fA2[i] = *(const bf16x8*)&sA[p][(wm + i * 16 + fr) * 64 + lc1];
        asm volatile("s_waitcnt lgkmcnt(8)" ::: "memory");  // A1 done (in-order)
        __builtin_amdgcn_sched_barrier(0);
        __builtin_amdgcn_s_setprio(1);
#pragma unroll
        for (int i = 0; i < 4; ++i)
#pragma unroll
            for (int j = 0; j < 4; ++j)
                acc[4 + i][j] = __builtin_amdgcn_mfma_f32_16x16x32_bf16(fA1[i], fB0[j], acc[4 + i][j], 0, 0, 0);
        __builtin_amdgcn_s_setprio(0);
        // group 3: A3 issued under A2's MFMA
#pragma unroll
        for (int i = 0; i < 4; ++i)
            fA3[i] = *(const bf16x8*)&sA[p][(wm + 64 + i * 16 + fr) * 64 + lc1];
        asm volatile("s_waitcnt lgkmcnt(4)" ::: "memory");  // B1+A2 done, A3 out
        __builtin_amdgcn_sched_barrier(0);
        __builtin_amdgcn_s_setprio(1);
#pragma unroll
        for (int i = 0; i < 4; ++i)
#pragma unroll
            for (int j = 0; j < 4; ++j)
                acc[i][j] = __builtin_amdgcn_mfma_f32_16x16x32_bf16(fA2[i], fB1[j], acc[i][j], 0, 0, 0);
        __builtin_amdgcn_s_setprio(0);
        asm volatile("s_waitcnt lgkmcnt(0)" ::: "memory");  // A3 done
        __builtin_amdgcn_sched_barrier(0);
        __builtin_amdgcn_s_setprio(1);
#pragma unroll
        for (int i = 0; i < 4; ++i)
#pragma unroll
            for (int j = 0; j < 4; ++j)
                acc[4 + i][j] = __builtin_amdgcn_mfma_f32_16x16x32_bf16(fA3[i], fB1[j], acc[4 + i][j], 0, 0, 0);
        __builtin_amdgcn_s_setprio(0);
    }

    // epilogue: j-innermost so adjacent 32B chunks issue back-to-back
    const int rb = g * 4;
    float bv[4];
#pragma unroll
    for (int j = 0; j < 4; ++j) bv[j] = bias ? bias[n0 + wn + j * 16 + fr] : 0.0f;
#pragma unroll
    for (int i = 0; i < 8; ++i) {
#pragma unroll
        for (int r = 0; r < 4; ++r) {
            const int m = m0 + wm + i * 16 + rb + r;
            CT* rowp = Cb + (size_t)m * N + n0 + wn + fr;
#pragma unroll
            for (int j = 0; j < 4; ++j)
                rowp[j * 16] = (CT)(acc[i][j][r] + bv[j]);
        }
    }
}

// ---------------------------------------------------------------------------
// context_local: per (chunk,bh) block computes LOCAL k-row max/sumexp and
// un-normalized partial ctxp (no cross-block sync; kernel boundary orders).
// ---------------------------------------------------------------------------
#define SKS 264   // LDS bf16 row stride (256 data + 8 pad)
__global__ __launch_bounds__(256) void context_local(const __bf16* __restrict__ qkv,
                                                     float* __restrict__ ctxp,
                                                     float* __restrict__ mstat,
                                                     float* __restrict__ sstat) {
    __shared__ __align__(16) __bf16 smem[2 * 64 * SKS];  // 67.6 KB; reused as f32 red[4][4096]
    __bf16* sk = smem;
    __bf16* sv = smem + 64 * SKS;
    const int chunk = blockIdx.x;
    const int bh = blockIdx.y;
    const int b = bh >> 3, h = bh & 7;
    const __bf16* kbase = qkv + (size_t)b * 1536 * L + (size_t)(512 + h * 64) * L;
    const __bf16* vbase = qkv + (size_t)b * 1536 * L + (size_t)(1024 + h * 64) * L;
    const int t = threadIdx.x;

    {
        const int d = t >> 2, noff = (t & 3) * 64;
        const int n0 = chunk * 256;
        const __bf16* kp = kbase + (size_t)d * L + n0 + noff;
        const __bf16* vp = vbase + (size_t)d * L + n0 + noff;
        bf16x8 kk[8];
        float m = -1e30f;
#pragma unroll
        for (int c = 0; c < 8; c++) {
            kk[c] = *(const bf16x8*)(kp + c * 8);
            bf16x8 vv = *(const bf16x8*)(vp + c * 8);
            *(bf16x8*)&sv[d * SKS + noff + c * 8] = vv;
#pragma unroll
            for (int j = 0; j < 8; j++) m = fmaxf(m, (float)kk[c][j]);
        }
        m = fmaxf(m, __shfl_xor(m, 1, 64));
        m = fmaxf(m, __shfl_xor(m, 2, 64));
        float s = 0.f;
#pragma unroll
        for (int c = 0; c < 8; c++) {
            bf16x8 ek;
#pragma unroll
            for (int j = 0; j < 8; j++) {
                float e = __expf((float)kk[c][j] - m);
                s += e;
                ek[j] = (__bf16)e;
            }
            *(bf16x8*)&sk[d * SKS + noff + c * 8] = ek;
        }
        s += __shfl_xor(s, 1, 64);
        s += __shfl_xor(s, 2, 64);
        if ((t & 3) == 0) {
            mstat[((size_t)chunk * 64 + bh) * 64 + d] = m;
            sstat[((size_t)chunk * 64 + bh) * 64 + d] = s;
        }
    }
    __syncthreads();

    const int wave = t >> 6, lane = t & 63;
    const int fr = lane & 15, kq = (lane >> 4) * 8;
    f32x4 acc[4][4];
#pragma unroll
    for (int i = 0; i < 4; i++)
#pragma unroll
        for (int j = 0; j < 4; j++) acc[i][j] = (f32x4)(0.0f);
#pragma unroll
    for (int kh = 0; kh < 2; kh++) {
        const int koff = wave * 64 + kh * 32 + kq;
        bf16x8 af[4], bfr[4];
#pragma unroll
        for (int i = 0; i < 4; i++) {
            af[i]  = *(const bf16x8*)&sk[(i * 16 + fr) * SKS + koff];
            bfr[i] = *(const bf16x8*)&sv[(i * 16 + fr) * SKS + koff];
        }
#pragma unroll
        for (int i = 0; i < 4; i++)
#pragma unroll
            for (int j = 0; j < 4; j++)
                acc[i][j] = __builtin_amdgcn_mfma_f32_16x16x32_bf16(af[i], bfr[j], acc[i][j], 0, 0, 0);
    }
    __syncthreads();

    float* red = (float*)smem;
    const int col = lane & 15, rbase = (lane >> 4) * 4;
#pragma unroll
    for (int i = 0; i < 4; i++)
#pragma unroll
        for (int j = 0; j < 4; j++)
#pragma unroll
            for (int r = 0; r < 4; r++) {
                const int dd = i * 16 + rbase + r;
                const int ee = j * 16 + col;
                red[wave * 4096 + dd * 64 + ee] = acc[i][j][r];
            }
    __syncthreads();
    float* cp = ctxp + ((size_t)chunk * 64 + bh) * 4096;
#pragma unroll
    for (int gg = 0; gg < 4; gg++) {
        const int idx = t * 16 + gg * 4;
        f32x4 s = *(const f32x4*)&red[idx];
        s += *(const f32x4*)&red[4096 + idx];
        s += *(const f32x4*)&red[8192 + idx];
        s += *(const f32x4*)&red[12288 + idx];
        *(f32x4*)&cp[idx] = s;
    }
}

// ---------------------------------------------------------------------------
// ctx_combine: online-softmax combine across chunks; transpose to bf16 ctxT.
// ---------------------------------------------------------------------------
__global__ __launch_bounds__(256) void ctx_combine(const float* __restrict__ ctxp,
                                                   const float* __restrict__ mstat,
                                                   const float* __restrict__ sstat,
                                                   __bf16* __restrict__ ctxT) {
    const int bh = blockIdx.x >> 2, quarter = blockIdx.x & 3;
    const int t = threadIdx.x;
    const int flat = quarter * 1024 + t * 4;
    const int d = flat >> 6, e0 = flat & 63;
    float M = -1e30f;
#pragma unroll
    for (int ch = 0; ch < NCH; ch++)
        M = fmaxf(M, mstat[((size_t)ch * 64 + bh) * 64 + d]);
    float S = 0.f;
    float w[NCH];
#pragma unroll
    for (int ch = 0; ch < NCH; ch++) {
        w[ch] = __expf(mstat[((size_t)ch * 64 + bh) * 64 + d] - M);
        S += sstat[((size_t)ch * 64 + bh) * 64 + d] * w[ch];
    }
    const float inv = 1.0f / S;
    f32x4 s = (f32x4)(0.0f);
#pragma unroll
    for (int ch = 0; ch < NCH; ch++) {
        f32x4 v = *(const f32x4*)&ctxp[((size_t)ch * 64 + bh) * 4096 + flat];
        s += v * w[ch];
    }
    __bf16* o = ctxT + (size_t)bh * 4096;
#pragma unroll
    for (int j = 0; j < 4; j++) o[(e0 + j) * 64 + d] = (__bf16)(s[j] * inv);
}

// ---------------------------------------------------------------------------
// pv_fused: per (bh, 256-col tile): q-softmax + MFMA vs ctxT -> bf16 outT.
// ---------------------------------------------------------------------------
#define SPS 66   // LDS row stride (bf16)
__global__ __launch_bounds__(256) void pv_fused(__bf16* __restrict__ qkv,
                                                const __bf16* __restrict__ ctxT) {
    __shared__ __align__(16) __bf16 sp[256 * SPS];
    __shared__ __align__(16) __bf16 sctx[64 * SPS];
    __shared__ float sinv[256];
    const int tileN = blockIdx.x;
    const int bh = blockIdx.y;
    const int b = bh >> 3, h = bh & 7;
    const int t = threadIdx.x;
    const int n0 = tileN * 256;
    const __bf16* qbase = qkv + (size_t)b * 1536 * L + (size_t)(h * 64) * L;

    {
        const int e = t >> 2, c = t & 3;
        const bf16x8* src = (const bf16x8*)(ctxT + ((size_t)bh * 64 + e) * 64 + c * 16);
        *(bf16x8*)&sctx[e * SPS + c * 16] = src[0];
        *(bf16x8*)&sctx[e * SPS + c * 16 + 8] = src[1];
    }

    float m = -1e30f;
    float qv[64];
#pragma unroll
    for (int d = 0; d < 64; d++) {
        qv[d] = (float)qbase[(size_t)d * L + n0 + t];
        m = fmaxf(m, qv[d]);
    }
    float s = 0.f;
#pragma unroll
    for (int d0 = 0; d0 < 64; d0 += 8) {
        bf16x8 ek;
#pragma unroll
        for (int j = 0; j < 8; j++) {
            float e = __expf(qv[d0 + j] - m);
            s += e;
            ek[j] = (__bf16)e;
        }
        *(bf16x8*)&sp[t * SPS + d0] = ek;
    }
    sinv[t] = 1.0f / s;
    __syncthreads();

    const int wave = t >> 6, lane = t & 63;
    const int wm = wave * 64;
    const int fr = lane & 15, kq = (lane >> 4) * 8;
    f32x4 acc[4][4];
#pragma unroll
    for (int i = 0; i < 4; i++)
#pragma unroll
        for (int j = 0; j < 4; j++) acc[i][j] = (f32x4)(0.0f);
#pragma unroll
    for (int kh = 0; kh < 2; kh++) {
        bf16x8 af[4], bfr[4];
#pragma unroll
        for (int i = 0; i < 4; i++)
            af[i] = *(const bf16x8*)&sp[(wm + i * 16 + fr) * SPS + kh * 32 + kq];
#pragma unroll
        for (int j = 0; j < 4; j++)
            bfr[j] = *(const bf16x8*)&sctx[(j * 16 + fr) * SPS + kh * 32 + kq];
#pragma unroll
        for (int i = 0; i < 4; i++)
#pragma unroll
            for (int j = 0; j < 4; j++)
                acc[i][j] = __builtin_amdgcn_mfma_f32_16x16x32_bf16(af[i], bfr[j], acc[i][j], 0, 0, 0);
    }

    __bf16* ob = qkv + (size_t)b * 1536 * L + (size_t)512 * L;
    const int col = lane & 15, rbase = (lane >> 4) * 4;
#pragma unroll
    for (int i = 0; i < 4; i++) {
#pragma unroll
        for (int r = 0; r < 4; r++) {
            const int nl = wm + i * 16 + rbase + r;
            const float inv = sinv[nl];
            const size_t rowoff = (size_t)(n0 + nl) * 512 + h * 64;
#pragma unroll
            for (int j = 0; j < 4; j++)
                ob[rowoff + j * 16 + col] = (__bf16)(acc[i][j][r] * inv);
        }
    }
}

// ---------------------------------------------------------------------------
extern "C" void kernel_launch(void* const* d_in, const int* in_sizes, int n_in,
                              void* d_out, int out_size, void* d_ws, size_t ws_size,
                              hipStream_t stream) {
    const float* x    = (const float*)d_in[0];
    const float* Wqkv = (const float*)d_in[1];
    const float* Wout = (const float*)d_in[2];
    const float* bout = (const float*)d_in[3];
    float* y = (float*)d_out;

    __bf16* qkv   = (__bf16*)d_ws;                               // 8*1536*4096 bf16
    float*  ctxp  = (float*)(qkv + (size_t)8 * 1536 * L);        // NCH*64*4096 f32
    __bf16* xb    = (__bf16*)(ctxp + (size_t)NCH * 64 * 4096);   // 8*4096*512 bf16
    __bf16* Wqb   = xb + (size_t)8 * 4096 * 512;                 // 1536*512 bf16
    __bf16* Wob   = Wqb + (size_t)1536 * 512;                    // 512*512 bf16
    float*  mstat = (float*)(Wob + (size_t)512 * 512);           // NCH*64*64 f32
    float*  sstat = mstat + (size_t)NCH * 64 * 64;               // NCH*64*64 f32
    __bf16* ctxT  = (__bf16*)(sstat + (size_t)NCH * 64 * 64);    // 64*4096 bf16

    const int convBlocks = (NX8 + NW18 + NW28 + 255) / 256;
    convert_all<<<dim3(convBlocks), 256, 0, stream>>>(x, Wqkv, Wout, xb);

    // qkv[b][o][l] = sum_d Wqkv[o][d] * x[b][l][d]   (M=1536, N=4096, K=512), bf16 out
    gemm_bf16_ws<1536, 4096, 512, __bf16><<<dim3(4096 / 256, 1536 / 256, 8), 512, 0, stream>>>(
        Wqb, 0, xb, (size_t)4096 * 512, qkv, (size_t)1536 * 4096, nullptr);

    context_local<<<dim3(NCH, 64), 256, 0, stream>>>(qkv, ctxp, mstat, sstat);
    ctx_combine<<<dim3(256), 256, 0, stream>>>(ctxp, mstat, sstat, ctxT);
    pv_fused<<<dim3(L / 256, 64), 256, 0, stream>>>(qkv, ctxT);

    // y[b][l][d] = sum_c outT[b][l][c] * Wout[d][c] + bout[d]  (M=4096, N=512, K=512), f32 out
    const __bf16* outT = qkv + (size_t)512 * L;
    gemm_bf16_ws<4096, 512, 512, float><<<dim3(512 / 256, 4096 / 256, 8), 512, 0, stream>>>(
        outT, (size_t)1536 * L, Wob, 0, y, (size_t)4096 * 512, bout);
}